// Round 17
// baseline (5957.671 us; speedup 1.0000x reference)
//
#include <hip/hip_runtime.h>
#include <cstdint>

typedef unsigned short u16;
typedef unsigned int u32;
typedef unsigned char u8;
typedef signed char s8;
typedef __bf16 bf16_t;
typedef bf16_t bf16x8 __attribute__((ext_vector_type(8)));
typedef float f32x4 __attribute__((ext_vector_type(4)));
typedef int i32x4 __attribute__((ext_vector_type(4)));

#define DMODEL 4096
#define DFF 11008
#define MROWS 8192

__device__ __forceinline__ u16 f2bf(float f) {
  u32 u = __builtin_bit_cast(u32, f);
  u += 0x7FFFu + ((u >> 16) & 1u);   // RNE
  return (u16)(u >> 16);
}
__device__ __forceinline__ float bf2f(u16 h) {
  return __builtin_bit_cast(float, (u32)h << 16);
}

// async global->LDS, 16B per lane, wave-uniform LDS base + lane*16
#define GLD16(gptr, lptr)                                                  \
  __builtin_amdgcn_global_load_lds(                                        \
      (const __attribute__((address_space(1))) u32*)(gptr),                \
      (__attribute__((address_space(3))) u32*)(lptr), 16, 0, 0)

#define BAR asm volatile("s_barrier" ::: "memory")
#define VM0 asm volatile("s_waitcnt vmcnt(0)" ::: "memory")
#define LGKM0 asm volatile("s_waitcnt lgkmcnt(0)" ::: "memory")

// ---- x -> int8 with per-row scale: x8 = round(x/sx), sx = rowmax/127 ----
__global__ void k_quant_x(const float* __restrict__ x, s8* __restrict__ x8,
                          float* __restrict__ sx) {
  const int row = blockIdx.x;
  const int t = threadIdx.x;            // 256
  const int lane = t & 63, wid = t >> 6;
  const float4* xr = reinterpret_cast<const float4*>(x + (size_t)row * DMODEL);
  float4 v[4];
  float m = 0.f;
#pragma unroll
  for (int i = 0; i < 4; ++i) {
    v[i] = xr[t * 4 + i];
    m = fmaxf(m, fmaxf(fmaxf(fabsf(v[i].x), fabsf(v[i].y)),
                       fmaxf(fabsf(v[i].z), fabsf(v[i].w))));
  }
#pragma unroll
  for (int off = 32; off >= 1; off >>= 1) m = fmaxf(m, __shfl_xor(m, off));
  __shared__ float wm[4];
  if (lane == 0) wm[wid] = m;
  __syncthreads();
  float mall = fmaxf(fmaxf(wm[0], wm[1]), fmaxf(wm[2], wm[3]));
  mall = fmaxf(mall, 1e-8f);
  const float inv = 127.f / mall;
  if (t == 0) sx[row] = mall / 127.f;
  uint4 o;
  u32 p[4];
#pragma unroll
  for (int i = 0; i < 4; ++i) {
    int a = (int)rintf(v[i].x * inv), b = (int)rintf(v[i].y * inv);
    int c = (int)rintf(v[i].z * inv), d = (int)rintf(v[i].w * inv);
    p[i] = (u32)(a & 255) | ((u32)(b & 255) << 8) | ((u32)(c & 255) << 16) |
           ((u32)(d & 255) << 24);
  }
  o.x = p[0]; o.y = p[1]; o.z = p[2]; o.w = p[3];
  reinterpret_cast<uint4*>(x8 + (size_t)row * DMODEL)[t] = o;
}

// ---- dequant to INT8 (q - z), transposed w8[N][K] (scales applied in GEMM) --
__global__ void k_dequant_T8(const int* __restrict__ q, const int* __restrict__ z,
                             s8* __restrict__ w8, int K, int N) {
  __shared__ s8 tile[32][40];
  const int t = threadIdx.x;
  const int n0 = blockIdx.x << 5, k0 = blockIdx.y << 5;
  {
    const int kr = t >> 3, n4 = (t & 7) << 2;
    const int k = k0 + kr, g = k >> 7;
    const int4 qv = *reinterpret_cast<const int4*>(&q[(size_t)k * N + n0 + n4]);
    const int4 zv = *reinterpret_cast<const int4*>(&z[(size_t)g * N + n0 + n4]);
    tile[kr][n4 + 0] = (s8)(qv.x - zv.x);
    tile[kr][n4 + 1] = (s8)(qv.y - zv.y);
    tile[kr][n4 + 2] = (s8)(qv.z - zv.z);
    tile[kr][n4 + 3] = (s8)(qv.w - zv.w);
  }
  __syncthreads();
  {
    const int n = t >> 3, ks = (t & 7) << 2;
    uchar4 o;
    o.x = (u8)tile[ks + 0][n];
    o.y = (u8)tile[ks + 1][n];
    o.z = (u8)tile[ks + 2][n];
    o.w = (u8)tile[ks + 3][n];
    *reinterpret_cast<uchar4*>(&w8[(size_t)(n0 + n) * K + k0 + ks]) = o;
  }
}

// ---- dequant to bf16 (for the down projection), transposed wT[N][K] ----
__global__ void k_dequant_T(const int* __restrict__ q, const int* __restrict__ z,
                            const float* __restrict__ s, u16* __restrict__ wT,
                            int K, int N) {
  __shared__ u16 tile[32][36];
  const int t = threadIdx.x;
  const int n0 = blockIdx.x << 5, k0 = blockIdx.y << 5;
  {
    const int kr = t >> 3, n4 = (t & 7) << 2;
    const int k = k0 + kr, g = k >> 7;
    const int4 qv = *reinterpret_cast<const int4*>(&q[(size_t)k * N + n0 + n4]);
    const int4 zv = *reinterpret_cast<const int4*>(&z[(size_t)g * N + n0 + n4]);
    const float4 sv = *reinterpret_cast<const float4*>(&s[(size_t)g * N + n0 + n4]);
    ushort4 o;
    o.x = f2bf((float)(qv.x - zv.x) * sv.x);
    o.y = f2bf((float)(qv.y - zv.y) * sv.y);
    o.z = f2bf((float)(qv.z - zv.z) * sv.z);
    o.w = f2bf((float)(qv.w - zv.w) * sv.w);
    *reinterpret_cast<ushort4*>(&tile[kr][n4]) = o;
  }
  __syncthreads();
  {
    const int n = t >> 3, ks = (t & 7) << 2;
    ushort4 o;
    o.x = tile[ks + 0][n];
    o.y = tile[ks + 1][n];
    o.z = tile[ks + 2][n];
    o.w = tile[ks + 3][n];
    *reinterpret_cast<ushort4*>(&wT[(size_t)(n0 + n) * K + k0 + ks]) = o;
  }
}

// ======== fused gate+up, INT8 MFMA, pair ping-pong (R15) + unroll-2 ========
// R16 structure with the group loop unrolled by 2 so the pair-buffer index
// pb is a COMPILE-TIME constant in each half: all 24 ds_read and 8 GLD16
// addresses per group become static base+offset instead of per-iteration
// runtime selects (the suspected unaccounted VALU). Numerics unchanged.
__global__ __launch_bounds__(512, 2) void k_fused_i8(
    const s8* __restrict__ A, const s8* __restrict__ Bg,
    const s8* __restrict__ Bu, const float* __restrict__ sx,
    const float* __restrict__ sg, const float* __restrict__ su,
    u16* __restrict__ H) {
  constexpr int Kdim = DMODEL;
  constexpr int ntiles = Kdim >> 6;  // 64 K-64 tiles = 32 pairs (= groups)
  __shared__ s8 Ab[2][2][256 * 64];   // [pairbuf][tile] 64KB
  __shared__ s8 Bgb[2][2][128 * 64];  // 32KB
  __shared__ s8 Bub[2][2][128 * 64];  // 32KB
  __shared__ u16 sclh[2][32 * 128];   // 16KB bf16: [op][group][col]

  const int midx = blockIdx.x & 31, nidx = blockIdx.x >> 5;
  const int m0 = midx << 8, n0 = nidx << 7;
  const int t = threadIdx.x;
  const int lane = t & 63;
  const int wid = t >> 6;
  const int wr = wid >> 2, wc = wid & 3;
  const int r16 = lane & 15, quad = lane >> 4;

  const int lrow = lane >> 2;
  const int sswz = ((lane & 3) ^ ((lrow >> 1) & 3)) << 4;  // byte offset
  const s8* Asrc = A + (size_t)(m0 + wid * 16 + lrow) * Kdim + sswz;
  const s8* Gsrc = Bg + (size_t)(n0 + wid * 16 + lrow) * Kdim + sswz;
  const s8* Usrc = Bu + (size_t)(n0 + wid * 16 + lrow) * Kdim + sswz;
  const size_t rstepA = (size_t)128 * Kdim;
  const int ldst = wid * 1024;  // byte offset of wave chunk in a tile region

#define STG(tt, pb_, ti) do {                                              \
    size_t ko = (size_t)((tt) & (ntiles - 1)) << 6;                        \
    GLD16(Asrc + ko,          &Ab[pb_][ti][ldst]);                         \
    GLD16(Asrc + ko + rstepA, &Ab[pb_][ti][ldst + 8192]);                  \
    GLD16(Gsrc + ko,          &Bgb[pb_][ti][ldst]);                        \
    GLD16(Usrc + ko,          &Bub[pb_][ti][ldst]);                        \
  } while (0)

  const int aswz = (quad ^ ((r16 >> 1) & 3)) << 4;
  const int abase = (wr * 128 + r16) * 64 + aswz;  // + mf*1024
  const int bbase = (wc * 32 + r16) * 64 + aswz;   // + nf*1024

  f32x4 facg[8][2], facu[8][2];
  const f32x4 zf = {0.f, 0.f, 0.f, 0.f};
#pragma unroll
  for (int mf = 0; mf < 8; ++mf)
#pragma unroll
    for (int nf = 0; nf < 2; ++nf) { facg[mf][nf] = zf; facu[mf][nf] = zf; }
  const i32x4 zi = {0, 0, 0, 0};

  // ---- prologue: scales -> LDS as bf16; stage pair 0 (tiles 0,1) ----
#pragma unroll
  for (int k = 0; k < 2; ++k) {
    int j = t + k * 512;          // float4 index 0..1023
    int g = j >> 5;               // [0,32)
    int c = (j & 31) << 2;        // [0,128)
    float4 vg = *reinterpret_cast<const float4*>(&sg[(size_t)g * DFF + n0 + c]);
    float4 vu = *reinterpret_cast<const float4*>(&su[(size_t)g * DFF + n0 + c]);
    ushort4 og, ou;
    og.x = f2bf(vg.x); og.y = f2bf(vg.y); og.z = f2bf(vg.z); og.w = f2bf(vg.w);
    ou.x = f2bf(vu.x); ou.y = f2bf(vu.y); ou.z = f2bf(vu.z); ou.w = f2bf(vu.w);
    *reinterpret_cast<ushort4*>(&sclh[0][g * 128 + c]) = og;
    *reinterpret_cast<ushort4*>(&sclh[1][g * 128 + c]) = ou;
  }
  STG(0, 0, 0); STG(1, 0, 1);
  VM0;
  LGKM0;  // scale ds_writes visible after the barrier
  BAR;

  const int sloc = wc * 32 + r16;  // scale column (+16 for nf=1)

  // one group: pb_ is a compile-time constant after unroll-2
#define GBODY(gi, pb_) do {                                                \
    i32x4 av0[8], bg_a[2], bg_b[2], bu_a[2], bu_b[2];                      \
    _Pragma("unroll") for (int mf = 0; mf < 8; ++mf)                       \
      av0[mf] = *reinterpret_cast<const i32x4*>(                           \
          &Ab[pb_][0][abase + mf * 1024]);                                 \
    _Pragma("unroll") for (int nf = 0; nf < 2; ++nf) {                     \
      bg_a[nf] = *reinterpret_cast<const i32x4*>(                          \
          &Bgb[pb_][0][bbase + nf * 1024]);                                \
      bu_a[nf] = *reinterpret_cast<const i32x4*>(                          \
          &Bub[pb_][0][bbase + nf * 1024]);                                \
      bg_b[nf] = *reinterpret_cast<const i32x4*>(                          \
          &Bgb[pb_][1][bbase + nf * 1024]);                                \
      bu_b[nf] = *reinterpret_cast<const i32x4*>(                          \
          &Bub[pb_][1][bbase + nf * 1024]);                                \
    }                                                                      \
    float s_g0 = bf2f(sclh[0][(gi) * 128 + sloc]);                         \
    float s_g1 = bf2f(sclh[0][(gi) * 128 + sloc + 16]);                    \
    float s_u0 = bf2f(sclh[1][(gi) * 128 + sloc]);                         \
    float s_u1 = bf2f(sclh[1][(gi) * 128 + sloc + 16]);                    \
    STG(2 * (gi) + 2, (pb_) ^ 1, 0);                                       \
    STG(2 * (gi) + 3, (pb_) ^ 1, 1);                                       \
    __builtin_amdgcn_s_setprio(1);                                         \
    _Pragma("unroll") for (int mf = 0; mf < 8; ++mf) {                     \
      i32x4 a1 = *reinterpret_cast<const i32x4*>(                          \
          &Ab[pb_][1][abase + mf * 1024]);                                 \
      i32x4 ig0 = __builtin_amdgcn_mfma_i32_16x16x64_i8(av0[mf], bg_a[0], zi, 0, 0, 0); \
      i32x4 ig1 = __builtin_amdgcn_mfma_i32_16x16x64_i8(av0[mf], bg_a[1], zi, 0, 0, 0); \
      i32x4 iu0 = __builtin_amdgcn_mfma_i32_16x16x64_i8(av0[mf], bu_a[0], zi, 0, 0, 0); \
      i32x4 iu1 = __builtin_amdgcn_mfma_i32_16x16x64_i8(av0[mf], bu_a[1], zi, 0, 0, 0); \
      ig0 = __builtin_amdgcn_mfma_i32_16x16x64_i8(a1, bg_b[0], ig0, 0, 0, 0); \
      ig1 = __builtin_amdgcn_mfma_i32_16x16x64_i8(a1, bg_b[1], ig1, 0, 0, 0); \
      iu0 = __builtin_amdgcn_mfma_i32_16x16x64_i8(a1, bu_b[0], iu0, 0, 0, 0); \
      iu1 = __builtin_amdgcn_mfma_i32_16x16x64_i8(a1, bu_b[1], iu1, 0, 0, 0); \
      _Pragma("unroll") for (int j = 0; j < 4; ++j) {                      \
        facg[mf][0][j] += (float)ig0[j] * s_g0;                            \
        facg[mf][1][j] += (float)ig1[j] * s_g1;                            \
        facu[mf][0][j] += (float)iu0[j] * s_u0;                            \
        facu[mf][1][j] += (float)iu1[j] * s_u1;                            \
      }                                                                    \
    }                                                                      \
    __builtin_amdgcn_s_setprio(0);                                         \
    VM0;                                                                   \
    BAR;                                                                   \
  } while (0)

  for (int i = 0; i < (ntiles >> 2); ++i) {   // 16 outer = 32 groups
    GBODY(2 * i, 0);
    GBODY(2 * i + 1, 1);
  }

  // epilogue: apply per-row x-scale, silu(g)*u -> bf16
  const int rb0 = m0 + wr * 128 + quad * 4;
  const int cb0 = n0 + wc * 32 + r16;
#pragma unroll
  for (int mf = 0; mf < 8; ++mf) {
#pragma unroll
    for (int j = 0; j < 4; ++j) {
      const int row = rb0 + mf * 16 + j;
      const float sxr = sx[row];
#pragma unroll
      for (int nf = 0; nf < 2; ++nf) {
        float gv = facg[mf][nf][j] * sxr;
        float uv = facu[mf][nf][j] * sxr;
        float sv = gv / (1.f + __expf(-gv));
        H[(size_t)row * DFF + cb0 + nf * 16] = f2bf(sv * uv);
      }
    }
  }
#undef STG
#undef GBODY
}

// ======== down GEMM, bf16, ping-pong (R16) + unroll-2 static buffers ======
__global__ __launch_bounds__(512, 2) void k_down(
    const u16* __restrict__ A, const u16* __restrict__ BT,
    float* __restrict__ C) {
  constexpr int Ndim = DMODEL, Kdim = DFF;
  __shared__ u16 As[2][2][256 * 32];  // [buf][khalf] 64KB total
  __shared__ u16 Bs[2][2][256 * 32];  // 64KB (LDS total 128KB)

  const int nidx = blockIdx.x & 15;   // n-major
  const int midx = blockIdx.x >> 4;
  const int m0 = midx << 8;
  const int n0 = nidx << 8;
  const int t = threadIdx.x;
  const int lane = t & 63;
  const int wid = t >> 6;
  const int wr = wid >> 2, wc = wid & 3;
  const int r16 = lane & 15, quad = lane >> 4;

  const int lrow4 = lane >> 2;
  const int sslot = ((lane & 3) ^ ((lane >> 3) & 3)) << 3;
  const u16* Asrc = A + (size_t)(m0 + wid * 16 + lrow4) * Kdim + sslot;
  const u16* Bsrc = BT + (size_t)(n0 + wid * 16 + lrow4) * Kdim + sslot;
  const size_t rstep = (size_t)128 * Kdim;
  const int lbo = wid * 512;
  constexpr int ntiles = Kdim >> 6;  // 172 (even)

#define SA(tt, kh, bf) do {                                                \
    int ttw = (tt) < ntiles ? (tt) : (tt) - ntiles;                        \
    size_t ko = ((size_t)ttw << 6) + ((kh) << 5);                          \
    GLD16(Asrc + ko,         &As[bf][kh][lbo]);                            \
    GLD16(Asrc + ko + rstep, &As[bf][kh][lbo + 4096]);                     \
  } while (0)
#define SB(tt, kh, bf) do {                                                \
    int ttw = (tt) < ntiles ? (tt) : (tt) - ntiles;                        \
    size_t ko = ((size_t)ttw << 6) + ((kh) << 5);                          \
    GLD16(Bsrc + ko,         &Bs[bf][kh][lbo]);                            \
    GLD16(Bsrc + ko + rstep, &Bs[bf][kh][lbo + 4096]);                     \
  } while (0)

  const int fragoff = (quad ^ ((r16 >> 1) & 3)) << 3;
  const int abase = (wr * 128 + r16) * 32 + fragoff;  // + mf*512
  const int bbase = (wc * 64 + r16) * 32 + fragoff;   // + nf*512

  f32x4 acc[8][4];
  const f32x4 zf = {0.f, 0.f, 0.f, 0.f};
#pragma unroll
  for (int mf = 0; mf < 8; ++mf)
#pragma unroll
    for (int nf = 0; nf < 4; ++nf) acc[mf][nf] = zf;

  // prologue: stage tile 0 into buf 0; publish.
  SA(0, 0, 0); SB(0, 0, 0); SA(0, 1, 0); SB(0, 1, 0);
  VM0;
  BAR;

  // one tile: bf_ compile-time after unroll-2
#define TBODY(tt, bf_) do {                                                \
    bf16x8 a0[8], b0[4], b1[4];                                            \
    _Pragma("unroll") for (int mf = 0; mf < 8; ++mf)                       \
      a0[mf] = *reinterpret_cast<const bf16x8*>(                           \
          &As[bf_][0][abase + mf * 512]);                                  \
    _Pragma("unroll") for (int nf = 0; nf < 4; ++nf) {                     \
      b0[nf] = *reinterpret_cast<const bf16x8*>(                           \
          &Bs[bf_][0][bbase + nf * 512]);                                  \
      b1[nf] = *reinterpret_cast<const bf16x8*>(                           \
          &Bs[bf_][1][bbase + nf * 512]);                                  \
    }                                                                      \
    SA((tt) + 1, 0, (bf_) ^ 1); SB((tt) + 1, 0, (bf_) ^ 1);                \
    SA((tt) + 1, 1, (bf_) ^ 1); SB((tt) + 1, 1, (bf_) ^ 1);                \
    __builtin_amdgcn_s_setprio(1);                                         \
    _Pragma("unroll") for (int mf = 0; mf < 8; ++mf)                       \
      _Pragma("unroll") for (int nf = 0; nf < 4; ++nf)                     \
        acc[mf][nf] = __builtin_amdgcn_mfma_f32_16x16x32_bf16(             \
            a0[mf], b0[nf], acc[mf][nf], 0, 0, 0);                         \
    bf16x8 a1[8];                                                          \
    _Pragma("unroll") for (int mf = 0; mf < 8; ++mf)                       \
      a1[mf] = *reinterpret_cast<const bf16x8*>(                           \
          &As[bf_][1][abase + mf * 512]);                                  \
    _Pragma("unroll") for (int mf = 0; mf < 8; ++mf)                       \
      _Pragma("unroll") for (int nf = 0; nf < 4; ++nf)                     \
        acc[mf][nf] = __builtin_amdgcn_mfma_f32_16x16x32_bf16(             \
            a1[mf], b1[nf], acc[mf][nf], 0, 0, 0);                         \
    __builtin_amdgcn_s_setprio(0);                                         \
    VM0;                                                                   \
    BAR;                                                                   \
  } while (0)

  for (int it = 0; it < (ntiles >> 1); ++it) {  // 86 outer = 172 tiles
    TBODY(2 * it, 0);
    TBODY(2 * it + 1, 1);
  }

  const int rb0 = m0 + wr * 128 + quad * 4;
  const int cb0 = n0 + wc * 64 + r16;
#pragma unroll
  for (int mf = 0; mf < 8; ++mf) {
#pragma unroll
    for (int nf = 0; nf < 4; ++nf) {
      f32x4 v = acc[mf][nf];
      int row = rb0 + mf * 16;
      int col = cb0 + nf * 16;
#pragma unroll
      for (int j = 0; j < 4; ++j)
        C[(size_t)(row + j) * Ndim + col] = v[j];
    }
  }
#undef SA
#undef SB
#undef TBODY
}

extern "C" void kernel_launch(void* const* d_in, const int* in_sizes, int n_in,
                              void* d_out, int out_size, void* d_ws, size_t ws_size,
                              hipStream_t stream) {
  const float* x  = (const float*)d_in[0];
  const int*   qg = (const int*)d_in[1];
  const int*   zg = (const int*)d_in[2];
  const float* sg = (const float*)d_in[3];
  const int*   qu = (const int*)d_in[4];
  const int*   zu = (const int*)d_in[5];
  const float* su = (const float*)d_in[6];
  const int*   qd = (const int*)d_in[7];
  const int*   zd = (const int*)d_in[8];
  const float* sd = (const float*)d_in[9];
  float* out = (float*)d_out;

  char* ws = (char*)d_ws;
  const size_t szX8 = (size_t)MROWS * DMODEL;        // 33.5 MB
  const size_t szSX = (size_t)MROWS * 4;             // 32 KB
  const size_t szW8 = (size_t)DMODEL * DFF;          // 45 MB
  const size_t szWD = (size_t)DFF * DMODEL * 2;      // 90 MB
  s8*    x8  = (s8*)(ws);
  float* sx  = (float*)(ws + szX8);
  s8*    wg8 = (s8*)(ws + szX8 + szSX);
  s8*    wu8 = (s8*)(ws + szX8 + szSX + szW8);
  u16*   wdT = (u16*)(ws + szX8 + szSX + 2 * szW8);
  u16*   h   = (u16*)(ws + szX8 + szSX + 2 * szW8 + szWD);  // [M][DFF] bf16

  k_quant_x<<<MROWS, 256, 0, stream>>>(x, x8, sx);
  k_dequant_T8<<<dim3(DFF / 32, DMODEL / 32), 256, 0, stream>>>(qg, zg, wg8, DMODEL, DFF);
  k_dequant_T8<<<dim3(DFF / 32, DMODEL / 32), 256, 0, stream>>>(qu, zu, wu8, DMODEL, DFF);
  k_dequant_T<<<dim3(DMODEL / 32, DFF / 32), 256, 0, stream>>>(qd, zd, sd, wdT, DFF, DMODEL);

  // h = silu(x@Wg)*(x@Wu): int8 MFMA pair ping-pong, grid 32m x 86n (m-major)
  k_fused_i8<<<(MROWS / 256) * (DFF / 128), 512, 0, stream>>>(
      x8, wg8, wu8, sx, sg, su, h);
  // out = h @ Wd: bf16 MFMA ping-pong, grid 32m x 16n (n-major)
  k_down<<<(MROWS / 256) * (DMODEL / 256), 512, 0, stream>>>(h, wdT, out);
}

// Round 18
// 1752.245 us; speedup vs baseline: 3.4000x; 3.4000x over previous
//
#include <hip/hip_runtime.h>
#include <cstdint>

typedef unsigned short u16;
typedef unsigned int u32;
typedef unsigned char u8;
typedef signed char s8;
typedef __bf16 bf16_t;
typedef bf16_t bf16x8 __attribute__((ext_vector_type(8)));
typedef float f32x4 __attribute__((ext_vector_type(4)));
typedef int i32x4 __attribute__((ext_vector_type(4)));

#define DMODEL 4096
#define DFF 11008
#define MROWS 8192

__device__ __forceinline__ u16 f2bf(float f) {
  u32 u = __builtin_bit_cast(u32, f);
  u += 0x7FFFu + ((u >> 16) & 1u);   // RNE
  return (u16)(u >> 16);
}
__device__ __forceinline__ float bf2f(u16 h) {
  return __builtin_bit_cast(float, (u32)h << 16);
}

// async global->LDS, 16B per lane, wave-uniform LDS base + lane*16
#define GLD16(gptr, lptr)                                                  \
  __builtin_amdgcn_global_load_lds(                                        \
      (const __attribute__((address_space(1))) u32*)(gptr),                \
      (__attribute__((address_space(3))) u32*)(lptr), 16, 0, 0)

#define BAR asm volatile("s_barrier" ::: "memory")
#define VM0 asm volatile("s_waitcnt vmcnt(0)" ::: "memory")
#define LGKM0 asm volatile("s_waitcnt lgkmcnt(0)" ::: "memory")

// ---- x -> int8 with per-row scale: x8 = round(x/sx), sx = rowmax/127 ----
__global__ void k_quant_x(const float* __restrict__ x, s8* __restrict__ x8,
                          float* __restrict__ sx) {
  const int row = blockIdx.x;
  const int t = threadIdx.x;            // 256
  const int lane = t & 63, wid = t >> 6;
  const float4* xr = reinterpret_cast<const float4*>(x + (size_t)row * DMODEL);
  float4 v[4];
  float m = 0.f;
#pragma unroll
  for (int i = 0; i < 4; ++i) {
    v[i] = xr[t * 4 + i];
    m = fmaxf(m, fmaxf(fmaxf(fabsf(v[i].x), fabsf(v[i].y)),
                       fmaxf(fabsf(v[i].z), fabsf(v[i].w))));
  }
#pragma unroll
  for (int off = 32; off >= 1; off >>= 1) m = fmaxf(m, __shfl_xor(m, off));
  __shared__ float wm[4];
  if (lane == 0) wm[wid] = m;
  __syncthreads();
  float mall = fmaxf(fmaxf(wm[0], wm[1]), fmaxf(wm[2], wm[3]));
  mall = fmaxf(mall, 1e-8f);
  const float inv = 127.f / mall;
  if (t == 0) sx[row] = mall / 127.f;
  uint4 o;
  u32 p[4];
#pragma unroll
  for (int i = 0; i < 4; ++i) {
    int a = (int)rintf(v[i].x * inv), b = (int)rintf(v[i].y * inv);
    int c = (int)rintf(v[i].z * inv), d = (int)rintf(v[i].w * inv);
    p[i] = (u32)(a & 255) | ((u32)(b & 255) << 8) | ((u32)(c & 255) << 16) |
           ((u32)(d & 255) << 24);
  }
  o.x = p[0]; o.y = p[1]; o.z = p[2]; o.w = p[3];
  reinterpret_cast<uint4*>(x8 + (size_t)row * DMODEL)[t] = o;
}

// ---- dequant to INT8 (q - z), transposed w8[N][K] (scales applied in GEMM) --
__global__ void k_dequant_T8(const int* __restrict__ q, const int* __restrict__ z,
                             s8* __restrict__ w8, int K, int N) {
  __shared__ s8 tile[32][40];
  const int t = threadIdx.x;
  const int n0 = blockIdx.x << 5, k0 = blockIdx.y << 5;
  {
    const int kr = t >> 3, n4 = (t & 7) << 2;
    const int k = k0 + kr, g = k >> 7;
    const int4 qv = *reinterpret_cast<const int4*>(&q[(size_t)k * N + n0 + n4]);
    const int4 zv = *reinterpret_cast<const int4*>(&z[(size_t)g * N + n0 + n4]);
    tile[kr][n4 + 0] = (s8)(qv.x - zv.x);
    tile[kr][n4 + 1] = (s8)(qv.y - zv.y);
    tile[kr][n4 + 2] = (s8)(qv.z - zv.z);
    tile[kr][n4 + 3] = (s8)(qv.w - zv.w);
  }
  __syncthreads();
  {
    const int n = t >> 3, ks = (t & 7) << 2;
    uchar4 o;
    o.x = (u8)tile[ks + 0][n];
    o.y = (u8)tile[ks + 1][n];
    o.z = (u8)tile[ks + 2][n];
    o.w = (u8)tile[ks + 3][n];
    *reinterpret_cast<uchar4*>(&w8[(size_t)(n0 + n) * K + k0 + ks]) = o;
  }
}

// ---- dequant to bf16 (for the down projection), transposed wT[N][K] ----
__global__ void k_dequant_T(const int* __restrict__ q, const int* __restrict__ z,
                            const float* __restrict__ s, u16* __restrict__ wT,
                            int K, int N) {
  __shared__ u16 tile[32][36];
  const int t = threadIdx.x;
  const int n0 = blockIdx.x << 5, k0 = blockIdx.y << 5;
  {
    const int kr = t >> 3, n4 = (t & 7) << 2;
    const int k = k0 + kr, g = k >> 7;
    const int4 qv = *reinterpret_cast<const int4*>(&q[(size_t)k * N + n0 + n4]);
    const int4 zv = *reinterpret_cast<const int4*>(&z[(size_t)g * N + n0 + n4]);
    const float4 sv = *reinterpret_cast<const float4*>(&s[(size_t)g * N + n0 + n4]);
    ushort4 o;
    o.x = f2bf((float)(qv.x - zv.x) * sv.x);
    o.y = f2bf((float)(qv.y - zv.y) * sv.y);
    o.z = f2bf((float)(qv.z - zv.z) * sv.z);
    o.w = f2bf((float)(qv.w - zv.w) * sv.w);
    *reinterpret_cast<ushort4*>(&tile[kr][n4]) = o;
  }
  __syncthreads();
  {
    const int n = t >> 3, ks = (t & 7) << 2;
    ushort4 o;
    o.x = tile[ks + 0][n];
    o.y = tile[ks + 1][n];
    o.z = tile[ks + 2][n];
    o.w = tile[ks + 3][n];
    *reinterpret_cast<ushort4*>(&wT[(size_t)(n0 + n) * K + k0 + ks]) = o;
  }
}

// ======== fused gate+up, INT8 MFMA, pair ping-pong (R15/R16, best) ========
// NOTE (R17 lesson): do NOT unroll the group loop by 2 — duplicating the
// fragment live ranges at this register pressure (128-reg acc + 96-reg
// frags) tips the allocator into scratch spill (WRITE_SIZE 176MB->9.1GB,
// 5.2x slowdown). Runtime pb select is the cheaper evil.
__global__ __launch_bounds__(512, 2) void k_fused_i8(
    const s8* __restrict__ A, const s8* __restrict__ Bg,
    const s8* __restrict__ Bu, const float* __restrict__ sx,
    const float* __restrict__ sg, const float* __restrict__ su,
    u16* __restrict__ H) {
  constexpr int Kdim = DMODEL;
  constexpr int ntiles = Kdim >> 6;  // 64 K-64 tiles = 32 pairs (= groups)
  __shared__ s8 Ab[2][2][256 * 64];   // [pairbuf][tile] 64KB
  __shared__ s8 Bgb[2][2][128 * 64];  // 32KB
  __shared__ s8 Bub[2][2][128 * 64];  // 32KB
  __shared__ u16 sclh[2][32 * 128];   // 16KB bf16: [op][group][col]

  const int midx = blockIdx.x & 31, nidx = blockIdx.x >> 5;
  const int m0 = midx << 8, n0 = nidx << 7;
  const int t = threadIdx.x;
  const int lane = t & 63;
  const int wid = t >> 6;
  const int wr = wid >> 2, wc = wid & 3;
  const int r16 = lane & 15, quad = lane >> 4;

  const int lrow = lane >> 2;
  const int sswz = ((lane & 3) ^ ((lrow >> 1) & 3)) << 4;  // byte offset
  const s8* Asrc = A + (size_t)(m0 + wid * 16 + lrow) * Kdim + sswz;
  const s8* Gsrc = Bg + (size_t)(n0 + wid * 16 + lrow) * Kdim + sswz;
  const s8* Usrc = Bu + (size_t)(n0 + wid * 16 + lrow) * Kdim + sswz;
  const size_t rstepA = (size_t)128 * Kdim;
  const int ldst = wid * 1024;  // byte offset of wave chunk in a tile region

#define STG(tt, pb_, ti) do {                                              \
    size_t ko = (size_t)((tt) & (ntiles - 1)) << 6;                        \
    GLD16(Asrc + ko,          &Ab[pb_][ti][ldst]);                         \
    GLD16(Asrc + ko + rstepA, &Ab[pb_][ti][ldst + 8192]);                  \
    GLD16(Gsrc + ko,          &Bgb[pb_][ti][ldst]);                        \
    GLD16(Usrc + ko,          &Bub[pb_][ti][ldst]);                        \
  } while (0)

  const int aswz = (quad ^ ((r16 >> 1) & 3)) << 4;
  const int abase = (wr * 128 + r16) * 64 + aswz;  // + mf*1024
  const int bbase = (wc * 32 + r16) * 64 + aswz;   // + nf*1024

  f32x4 facg[8][2], facu[8][2];
  const f32x4 zf = {0.f, 0.f, 0.f, 0.f};
#pragma unroll
  for (int mf = 0; mf < 8; ++mf)
#pragma unroll
    for (int nf = 0; nf < 2; ++nf) { facg[mf][nf] = zf; facu[mf][nf] = zf; }
  const i32x4 zi = {0, 0, 0, 0};

  // ---- prologue: scales -> LDS as bf16; stage pair 0 (tiles 0,1) ----
#pragma unroll
  for (int k = 0; k < 2; ++k) {
    int j = t + k * 512;          // float4 index 0..1023
    int g = j >> 5;               // [0,32)
    int c = (j & 31) << 2;        // [0,128)
    float4 vg = *reinterpret_cast<const float4*>(&sg[(size_t)g * DFF + n0 + c]);
    float4 vu = *reinterpret_cast<const float4*>(&su[(size_t)g * DFF + n0 + c]);
    ushort4 og, ou;
    og.x = f2bf(vg.x); og.y = f2bf(vg.y); og.z = f2bf(vg.z); og.w = f2bf(vg.w);
    ou.x = f2bf(vu.x); ou.y = f2bf(vu.y); ou.z = f2bf(vu.z); ou.w = f2bf(vu.w);
    *reinterpret_cast<ushort4*>(&sclh[0][g * 128 + c]) = og;
    *reinterpret_cast<ushort4*>(&sclh[1][g * 128 + c]) = ou;
  }
  STG(0, 0, 0); STG(1, 0, 1);
  VM0;
  LGKM0;  // scale ds_writes visible after the barrier
  BAR;

  const int sloc = wc * 32 + r16;  // scale column (+16 for nf=1)

  for (int i = 0; i < (ntiles >> 1); ++i) {   // 32 pairs (= groups)
    const int pb = i & 1;
    // upfront frag reads: A tile0 (8) + B both tiles (8) = 16 ds_read_b128
    i32x4 av0[8], bg_a[2], bg_b[2], bu_a[2], bu_b[2];
#pragma unroll
    for (int mf = 0; mf < 8; ++mf)
      av0[mf] = *reinterpret_cast<const i32x4*>(&Ab[pb][0][abase + mf * 1024]);
#pragma unroll
    for (int nf = 0; nf < 2; ++nf) {
      bg_a[nf] = *reinterpret_cast<const i32x4*>(&Bgb[pb][0][bbase + nf * 1024]);
      bu_a[nf] = *reinterpret_cast<const i32x4*>(&Bub[pb][0][bbase + nf * 1024]);
      bg_b[nf] = *reinterpret_cast<const i32x4*>(&Bgb[pb][1][bbase + nf * 1024]);
      bu_b[nf] = *reinterpret_cast<const i32x4*>(&Bub[pb][1][bbase + nf * 1024]);
    }
    // group scales from LDS (bf16 -> f32)
    float s_g0 = bf2f(sclh[0][i * 128 + sloc]);
    float s_g1 = bf2f(sclh[0][i * 128 + sloc + 16]);
    float s_u0 = bf2f(sclh[1][i * 128 + sloc]);
    float s_u1 = bf2f(sclh[1][i * 128 + sloc + 16]);
    // stage next pair into the other pair-buf (fully read last iter)
    STG(2 * i + 2, pb ^ 1, 0);
    STG(2 * i + 3, pb ^ 1, 1);
    __builtin_amdgcn_s_setprio(1);
#pragma unroll
    for (int mf = 0; mf < 8; ++mf) {
      i32x4 a1 = *reinterpret_cast<const i32x4*>(&Ab[pb][1][abase + mf * 1024]);
      i32x4 ig0 = __builtin_amdgcn_mfma_i32_16x16x64_i8(av0[mf], bg_a[0], zi, 0, 0, 0);
      i32x4 ig1 = __builtin_amdgcn_mfma_i32_16x16x64_i8(av0[mf], bg_a[1], zi, 0, 0, 0);
      i32x4 iu0 = __builtin_amdgcn_mfma_i32_16x16x64_i8(av0[mf], bu_a[0], zi, 0, 0, 0);
      i32x4 iu1 = __builtin_amdgcn_mfma_i32_16x16x64_i8(av0[mf], bu_a[1], zi, 0, 0, 0);
      ig0 = __builtin_amdgcn_mfma_i32_16x16x64_i8(a1, bg_b[0], ig0, 0, 0, 0);
      ig1 = __builtin_amdgcn_mfma_i32_16x16x64_i8(a1, bg_b[1], ig1, 0, 0, 0);
      iu0 = __builtin_amdgcn_mfma_i32_16x16x64_i8(a1, bu_b[0], iu0, 0, 0, 0);
      iu1 = __builtin_amdgcn_mfma_i32_16x16x64_i8(a1, bu_b[1], iu1, 0, 0, 0);
#pragma unroll
      for (int j = 0; j < 4; ++j) {
        facg[mf][0][j] += (float)ig0[j] * s_g0;
        facg[mf][1][j] += (float)ig1[j] * s_g1;
        facu[mf][0][j] += (float)iu0[j] * s_u0;
        facu[mf][1][j] += (float)iu1[j] * s_u1;
      }
    }
    __builtin_amdgcn_s_setprio(0);
    VM0;   // staged loads had the whole cluster to land
    BAR;
  }

  // epilogue: apply per-row x-scale, silu(g)*u -> bf16
  const int rb0 = m0 + wr * 128 + quad * 4;
  const int cb0 = n0 + wc * 32 + r16;
#pragma unroll
  for (int mf = 0; mf < 8; ++mf) {
#pragma unroll
    for (int j = 0; j < 4; ++j) {
      const int row = rb0 + mf * 16 + j;
      const float sxr = sx[row];
#pragma unroll
      for (int nf = 0; nf < 2; ++nf) {
        float gv = facg[mf][nf][j] * sxr;
        float uv = facu[mf][nf][j] * sxr;
        float sv = gv / (1.f + __expf(-gv));
        H[(size_t)row * DFF + cb0 + nf * 16] = f2bf(sv * uv);
      }
    }
  }
#undef STG
}

// ======== down GEMM, bf16, pair ping-pong (R16, best) ========
__global__ __launch_bounds__(512, 2) void k_down(
    const u16* __restrict__ A, const u16* __restrict__ BT,
    float* __restrict__ C) {
  constexpr int Ndim = DMODEL, Kdim = DFF;
  __shared__ u16 As[2][2][256 * 32];  // [buf][khalf] 64KB total
  __shared__ u16 Bs[2][2][256 * 32];  // 64KB (LDS total 128KB)

  const int nidx = blockIdx.x & 15;   // n-major
  const int midx = blockIdx.x >> 4;
  const int m0 = midx << 8;
  const int n0 = nidx << 8;
  const int t = threadIdx.x;
  const int lane = t & 63;
  const int wid = t >> 6;
  const int wr = wid >> 2, wc = wid & 3;
  const int r16 = lane & 15, quad = lane >> 4;

  const int lrow4 = lane >> 2;
  const int sslot = ((lane & 3) ^ ((lane >> 3) & 3)) << 3;
  const u16* Asrc = A + (size_t)(m0 + wid * 16 + lrow4) * Kdim + sslot;
  const u16* Bsrc = BT + (size_t)(n0 + wid * 16 + lrow4) * Kdim + sslot;
  const size_t rstep = (size_t)128 * Kdim;
  const int lbo = wid * 512;
  constexpr int ntiles = Kdim >> 6;  // 172

#define SA(tt, kh, bf) do {                                                \
    int ttw = (tt) < ntiles ? (tt) : (tt) - ntiles;                        \
    size_t ko = ((size_t)ttw << 6) + ((kh) << 5);                          \
    GLD16(Asrc + ko,         &As[bf][kh][lbo]);                            \
    GLD16(Asrc + ko + rstep, &As[bf][kh][lbo + 4096]);                     \
  } while (0)
#define SB(tt, kh, bf) do {                                                \
    int ttw = (tt) < ntiles ? (tt) : (tt) - ntiles;                        \
    size_t ko = ((size_t)ttw << 6) + ((kh) << 5);                          \
    GLD16(Bsrc + ko,         &Bs[bf][kh][lbo]);                            \
    GLD16(Bsrc + ko + rstep, &Bs[bf][kh][lbo + 4096]);                     \
  } while (0)

  const int fragoff = (quad ^ ((r16 >> 1) & 3)) << 3;
  const int abase = (wr * 128 + r16) * 32 + fragoff;  // + mf*512
  const int bbase = (wc * 64 + r16) * 32 + fragoff;   // + nf*512

  f32x4 acc[8][4];
  const f32x4 zf = {0.f, 0.f, 0.f, 0.f};
#pragma unroll
  for (int mf = 0; mf < 8; ++mf)
#pragma unroll
    for (int nf = 0; nf < 4; ++nf) acc[mf][nf] = zf;

  // prologue: stage tile 0 into buf 0; publish.
  SA(0, 0, 0); SB(0, 0, 0); SA(0, 1, 0); SB(0, 1, 0);
  VM0;
  BAR;

  for (int tt = 0; tt < ntiles; ++tt) {
    const int bf = tt & 1;
    // upfront frag reads: A-kh0 (8) + B-kh0 (4) + B-kh1 (4)
    bf16x8 a0[8], b0[4], b1[4];
#pragma unroll
    for (int mf = 0; mf < 8; ++mf)
      a0[mf] = *reinterpret_cast<const bf16x8*>(&As[bf][0][abase + mf * 512]);
#pragma unroll
    for (int nf = 0; nf < 4; ++nf) {
      b0[nf] = *reinterpret_cast<const bf16x8*>(&Bs[bf][0][bbase + nf * 512]);
      b1[nf] = *reinterpret_cast<const bf16x8*>(&Bs[bf][1][bbase + nf * 512]);
    }
    // stage next tile into the other buf (fully read last iter)
    SA(tt + 1, 0, bf ^ 1); SB(tt + 1, 0, bf ^ 1);
    SA(tt + 1, 1, bf ^ 1); SB(tt + 1, 1, bf ^ 1);
    __builtin_amdgcn_s_setprio(1);
#pragma unroll
    for (int mf = 0; mf < 8; ++mf)
#pragma unroll
      for (int nf = 0; nf < 4; ++nf)
        acc[mf][nf] = __builtin_amdgcn_mfma_f32_16x16x32_bf16(
            a0[mf], b0[nf], acc[mf][nf], 0, 0, 0);
    bf16x8 a1[8];
#pragma unroll
    for (int mf = 0; mf < 8; ++mf)
      a1[mf] = *reinterpret_cast<const bf16x8*>(&As[bf][1][abase + mf * 512]);
#pragma unroll
    for (int mf = 0; mf < 8; ++mf)
#pragma unroll
      for (int nf = 0; nf < 4; ++nf)
        acc[mf][nf] = __builtin_amdgcn_mfma_f32_16x16x32_bf16(
            a1[mf], b1[nf], acc[mf][nf], 0, 0, 0);
    __builtin_amdgcn_s_setprio(0);
    VM0;   // staged loads had the whole cluster to land
    BAR;
  }

  const int rb0 = m0 + wr * 128 + quad * 4;
  const int cb0 = n0 + wc * 64 + r16;
#pragma unroll
  for (int mf = 0; mf < 8; ++mf) {
#pragma unroll
    for (int nf = 0; nf < 4; ++nf) {
      f32x4 v = acc[mf][nf];
      int row = rb0 + mf * 16;
      int col = cb0 + nf * 16;
#pragma unroll
      for (int j = 0; j < 4; ++j)
        C[(size_t)(row + j) * Ndim + col] = v[j];
    }
  }
#undef SA
#undef SB
}

extern "C" void kernel_launch(void* const* d_in, const int* in_sizes, int n_in,
                              void* d_out, int out_size, void* d_ws, size_t ws_size,
                              hipStream_t stream) {
  const float* x  = (const float*)d_in[0];
  const int*   qg = (const int*)d_in[1];
  const int*   zg = (const int*)d_in[2];
  const float* sg = (const float*)d_in[3];
  const int*   qu = (const int*)d_in[4];
  const int*   zu = (const int*)d_in[5];
  const float* su = (const float*)d_in[6];
  const int*   qd = (const int*)d_in[7];
  const int*   zd = (const int*)d_in[8];
  const float* sd = (const float*)d_in[9];
  float* out = (float*)d_out;

  char* ws = (char*)d_ws;
  const size_t szX8 = (size_t)MROWS * DMODEL;        // 33.5 MB
  const size_t szSX = (size_t)MROWS * 4;             // 32 KB
  const size_t szW8 = (size_t)DMODEL * DFF;          // 45 MB
  const size_t szWD = (size_t)DFF * DMODEL * 2;      // 90 MB
  s8*    x8  = (s8*)(ws);
  float* sx  = (float*)(ws + szX8);
  s8*    wg8 = (s8*)(ws + szX8 + szSX);
  s8*    wu8 = (s8*)(ws + szX8 + szSX + szW8);
  u16*   wdT = (u16*)(ws + szX8 + szSX + 2 * szW8);
  u16*   h   = (u16*)(ws + szX8 + szSX + 2 * szW8 + szWD);  // [M][DFF] bf16

  k_quant_x<<<MROWS, 256, 0, stream>>>(x, x8, sx);
  k_dequant_T8<<<dim3(DFF / 32, DMODEL / 32), 256, 0, stream>>>(qg, zg, wg8, DMODEL, DFF);
  k_dequant_T8<<<dim3(DFF / 32, DMODEL / 32), 256, 0, stream>>>(qu, zu, wu8, DMODEL, DFF);
  k_dequant_T<<<dim3(DMODEL / 32, DFF / 32), 256, 0, stream>>>(qd, zd, sd, wdT, DFF, DMODEL);

  // h = silu(x@Wg)*(x@Wu): int8 MFMA pair ping-pong, grid 32m x 86n (m-major)
  k_fused_i8<<<(MROWS / 256) * (DFF / 128), 512, 0, stream>>>(
      x8, wg8, wu8, sx, sg, su, h);
  // out = h @ Wd: bf16 MFMA pair ping-pong, grid 32m x 16n (n-major)
  k_down<<<(MROWS / 256) * (DMODEL / 256), 512, 0, stream>>>(h, wdT, out);
}